// Round 3
// baseline (137.226 us; speedup 1.0000x reference)
//
#include <hip/hip_runtime.h>
#include <hip/hip_bf16.h>
#include <cstdint>

#define NN 100000
#define DEG 16
#define FF 256
#define UU 128

typedef __attribute__((ext_vector_type(8))) short short8;
typedef __attribute__((ext_vector_type(4))) float f32x4;

__device__ __forceinline__ unsigned short f2bf(float x) {
    uint32_t u = __builtin_bit_cast(uint32_t, x);
    uint32_t r = (u + 0x7fffu + ((u >> 16) & 1u)) >> 16;
    return (unsigned short)r;
}
__device__ __forceinline__ float bf2f(unsigned short b) {
    return __builtin_bit_cast(float, (uint32_t)b << 16);
}
__device__ __forceinline__ uint32_t cvt_pk_bf16(float lo, float hi) {
    uint32_t r;
    asm("v_cvt_pk_bf16_f32 %0, %1, %2" : "=v"(r) : "v"(lo), "v"(hi));
    return r;
}

// Pre-kernel: W [256][128] f32 -> Wt [128][256] bf16 (transposed, 64 KB, L2-hot).
__global__ void k_convW(const float* __restrict__ W, unsigned short* __restrict__ Wt) {
    int i = blockIdx.x * 256 + threadIdx.x;  // 32768 elements
    int k = i >> 7, c = i & 127;
    Wt[c * 256 + k] = f2bf(W[i]);
}

// Main GEMM: h = ns @ W via bf16 MFMA. Block = 64 rows x 128 cols, 4 waves,
// wave w owns cols [w*32, w*32+32). NO LDS / NO barriers in the main loop:
// A fragments loaded directly from global (row-clamped), converted to bf16
// in-register with v_cvt_pk_bf16_f32. B frags in registers. Epilogue round-
// trips acc through LDS for coalesced bf16 store + fused attention dots.
__global__ __launch_bounds__(256, 2) void k_gemm(
    const float* __restrict__ ns, const unsigned short* __restrict__ Wt,
    const float* __restrict__ ka, unsigned short* __restrict__ hb,
    float* __restrict__ a_src, float* __restrict__ a_dst)
{
    __shared__ char smem[64 * 136 * 2 + 1024];  // Ht[64][136] ushort + ka[256] f32
    float* ka_s = (float*)(smem + 64 * 136 * 2);
    const int t = threadIdx.x;
    const int lane = t & 63;
    const int w = t >> 6;
    const int row0 = blockIdx.x * 64;
    const int lrow = lane & 15;
    const int khalf = lane >> 4;

    ka_s[t] = ka[t];

    // ---- B fragments (registers): bfrag[nt][ks], (lane,elem)->k = khalf*8+ks*32+e ----
    short8 bfrag[2][8];
    {
        const int col0 = w * 32 + lrow;
        #pragma unroll
        for (int nt = 0; nt < 2; ++nt) {
            const unsigned short* wp = Wt + (size_t)(col0 + nt * 16) * 256 + khalf * 8;
            #pragma unroll
            for (int ks = 0; ks < 8; ++ks)
                bfrag[nt][ks] = *(const short8*)(wp + ks * 32);
        }
    }

    // ---- A row pointers (clamped; same (lane,elem)->k map as B) ----
    const float* arow[4];
    #pragma unroll
    for (int mt = 0; mt < 4; ++mt) {
        int gr = row0 + mt * 16 + lrow;
        if (gr > NN - 1) gr = NN - 1;
        arow[mt] = ns + (size_t)gr * FF + khalf * 8;
    }

    f32x4 acc[4][2];
    #pragma unroll
    for (int mt = 0; mt < 4; ++mt)
        #pragma unroll
        for (int nt = 0; nt < 2; ++nt)
            acc[mt][nt] = (f32x4){0.f, 0.f, 0.f, 0.f};

    // ---- K-loop: per ks, 8 direct dwordx4 loads + 4 cvt_pk packs + 8 MFMA ----
    #pragma unroll
    for (int ks = 0; ks < 8; ++ks) {
        short8 a[4];
        #pragma unroll
        for (int mt = 0; mt < 4; ++mt) {
            float4 x0 = *(const float4*)(arow[mt] + ks * 32);
            float4 x1 = *(const float4*)(arow[mt] + ks * 32 + 4);
            uint4 u;
            u.x = cvt_pk_bf16(x0.x, x0.y);
            u.y = cvt_pk_bf16(x0.z, x0.w);
            u.z = cvt_pk_bf16(x1.x, x1.y);
            u.w = cvt_pk_bf16(x1.z, x1.w);
            a[mt] = __builtin_bit_cast(short8, u);
        }
        #pragma unroll
        for (int mt = 0; mt < 4; ++mt)
            #pragma unroll
            for (int nt = 0; nt < 2; ++nt)
                acc[mt][nt] = __builtin_amdgcn_mfma_f32_16x16x32_bf16(
                    a[mt], bfrag[nt][ks], acc[mt][nt], 0, 0, 0);
    }

    __syncthreads();  // only for smem reuse ordering across epilogue phases

    // ---- acc -> Ht (row stride 136 shorts breaks bank aliasing) ----
    unsigned short* Hs = (unsigned short*)smem;
    {
        const int wcol = w * 32;
        #pragma unroll
        for (int mt = 0; mt < 4; ++mt)
            #pragma unroll
            for (int nt = 0; nt < 2; ++nt)
                #pragma unroll
                for (int r = 0; r < 4; ++r) {
                    int row = mt * 16 + khalf * 4 + r;
                    int col = wcol + nt * 16 + lrow;
                    Hs[row * 136 + col] = f2bf(acc[mt][nt][r]);
                }
    }
    __syncthreads();

    // ---- coalesced hb store + attention dots (4 threads per row) ----
    {
        int row = t >> 2, q = t & 3;
        int gr = row0 + row;
        float ps = 0.f, pd = 0.f;
        short8 hv[4];
        #pragma unroll
        for (int j = 0; j < 4; ++j) {
            hv[j] = *(const short8*)(Hs + row * 136 + q * 32 + j * 8);
            #pragma unroll
            for (int e = 0; e < 8; ++e) {
                float hf = bf2f((unsigned short)hv[j][e]);
                int c = q * 32 + j * 8 + e;
                ps = fmaf(hf, ka_s[c], ps);
                pd = fmaf(hf, ka_s[UU + c], pd);
            }
        }
        if (gr < NN) {
            short8* op = (short8*)(hb + (size_t)gr * UU + q * 32);
            op[0] = hv[0]; op[1] = hv[1]; op[2] = hv[2]; op[3] = hv[3];
        }
        ps += __shfl_xor(ps, 1, 64); ps += __shfl_xor(ps, 2, 64);
        pd += __shfl_xor(pd, 1, 64); pd += __shfl_xor(pd, 2, 64);
        if (q == 0 && gr < NN) { a_src[gr] = ps; a_dst[gr] = pd; }
    }
}

// Aggregation: 4 nodes per wave (16-lane group per node). Scores computed once
// per edge; softmax sum via intra-group shfl_xor; PV gather: each lane owns
// 8 output dims (16B of the bf16 row) -> one b128 load per lane covers
// 4 rows x 256B per instruction. Output: 2x float4 per lane, 512B/group.
__global__ __launch_bounds__(256, 4) void k_agg(
    const int* __restrict__ edges, const float* __restrict__ ew,
    const float* __restrict__ a_src, const float* __restrict__ a_dst,
    const unsigned short* __restrict__ hb, float* __restrict__ out)
{
    const int t = threadIdx.x;
    const int lane = t & 63;
    const int wv = t >> 6;
    const int g = lane >> 4;       // node sub-index within wave
    const int q = lane & 15;       // edge slot / dim slot
    const int n = blockIdx.x * 16 + wv * 4 + g;
    const int ei = n * DEG + q;

    const int dst = edges[2 * ei + 1];
    const float w = ew[ei];
    const float x0 = w * (a_src[n] + a_dst[dst]);
    float x = x0 > 0.f ? x0 : 0.2f * x0;        // leaky_relu, slope 0.2
    x = fminf(2.f, fmaxf(-2.f, x));             // clip
    const float s = __expf(x) ;

    float ssum = s;                              // xor masks <16 stay in-group
    ssum += __shfl_xor(ssum, 1, 64);
    ssum += __shfl_xor(ssum, 2, 64);
    ssum += __shfl_xor(ssum, 4, 64);
    ssum += __shfl_xor(ssum, 8, 64);
    const float norm = s / ssum;

    const int gbase = lane & 48;
    const unsigned short* hp = hb + q * 8;
    float acc[8];
    #pragma unroll
    for (int d = 0; d < 8; ++d) acc[d] = 0.f;

    #pragma unroll
    for (int j = 0; j < 16; ++j) {
        const int dj = __shfl(dst, gbase | j, 64);
        const float nj = __shfl(norm, gbase | j, 64);
        const uint4 hv = *(const uint4*)(hp + (size_t)dj * UU);
        acc[0] = fmaf(nj, __builtin_bit_cast(float, hv.x << 16), acc[0]);
        acc[1] = fmaf(nj, __builtin_bit_cast(float, hv.x & 0xffff0000u), acc[1]);
        acc[2] = fmaf(nj, __builtin_bit_cast(float, hv.y << 16), acc[2]);
        acc[3] = fmaf(nj, __builtin_bit_cast(float, hv.y & 0xffff0000u), acc[3]);
        acc[4] = fmaf(nj, __builtin_bit_cast(float, hv.z << 16), acc[4]);
        acc[5] = fmaf(nj, __builtin_bit_cast(float, hv.z & 0xffff0000u), acc[5]);
        acc[6] = fmaf(nj, __builtin_bit_cast(float, hv.w << 16), acc[6]);
        acc[7] = fmaf(nj, __builtin_bit_cast(float, hv.w & 0xffff0000u), acc[7]);
    }

    float* op = out + (size_t)n * UU + q * 8;
    float4 o0, o1;
    o0.x = acc[0]; o0.y = acc[1]; o0.z = acc[2]; o0.w = acc[3];
    o1.x = acc[4]; o1.y = acc[5]; o1.z = acc[6]; o1.w = acc[7];
    *(float4*)op = o0;
    *(float4*)(op + 4) = o1;
}

extern "C" void kernel_launch(void* const* d_in, const int* in_sizes, int n_in,
                              void* d_out, int out_size, void* d_ws, size_t ws_size,
                              hipStream_t stream) {
    const float* ns    = (const float*)d_in[0];  // [1, N, 256] f32
    const int*   edges = (const int*)d_in[1];    // [1, E, 2] i32, src sorted
    const float* ew    = (const float*)d_in[2];  // [1, E] f32
    const float* W     = (const float*)d_in[3];  // [256, 128] f32
    const float* ka    = (const float*)d_in[4];  // [256, 1] f32
    float* out = (float*)d_out;                  // [N, 128] f32

    char* ws = (char*)d_ws;
    unsigned short* hb = (unsigned short*)ws;                    // N*128 bf16 = 25.6 MB
    float* a_src = (float*)(ws + (size_t)NN * UU * 2);           // N f32
    float* a_dst = a_src + NN;                                   // N f32
    unsigned short* Wt = (unsigned short*)(ws + (size_t)NN * UU * 2 + 2 * (size_t)NN * 4);  // 64 KB

    k_convW<<<FF * UU / 256, 256, 0, stream>>>(W, Wt);                    // 128 blocks
    k_gemm<<<(NN + 63) / 64, 256, 0, stream>>>(ns, Wt, ka, hb, a_src, a_dst);  // 1563 blocks
    k_agg<<<NN / 16, 256, 0, stream>>>(edges, ew, a_src, a_dst, hb, out); // 6250 blocks
}